// Round 3
// baseline (987.824 us; speedup 1.0000x reference)
//
#include <hip/hip_runtime.h>
#include <hip/hip_bf16.h>
#include <math.h>

// GNN: 3-layer GCN + BN + GELU + residual + meanpool + MLP -> scalar.
// R3: channel-chunked aggregation with XCD-affine chunk placement (3.2MB chunk
// fits one XCD's 4MB L2 -> gathers become L2 hits instead of L3 traffic);
// chunked U_t[chunk][node][8] layout written by GEMM epilogue; BN stats fused
// into agg/gemm epilogues (stats passes deleted); x transposed+prescaled once.

__device__ __forceinline__ float gelu_f(float x) {
    return 0.5f * x * (1.0f + erff(x * 0.7071067811865476f));
}

__device__ __forceinline__ int wave_incl_scan(int v, int lane) {
#pragma unroll
    for (int off = 1; off < 64; off <<= 1) {
        int t = __shfl_up(v, (unsigned)off, 64);
        if (lane >= off) v += t;
    }
    return v;
}

// ---- init: deg = 1.0 (self loop), zero double accumulators ----
__global__ void init_kernel(float* __restrict__ deg, double* __restrict__ dbls,
                            int n, int ndbl) {
    int i = blockIdx.x * 256 + threadIdx.x;
    if (i < n) deg[i] = 1.0f;
    if (i < ndbl) dbls[i] = 0.0;
}

__global__ void degree_kernel(const int* __restrict__ col, float* __restrict__ deg, int E) {
    int e = blockIdx.x * 256 + threadIdx.x;
    if (e < E) atomicAdd(&deg[col[e]], 1.0f);
}

__global__ __launch_bounds__(256) void scan1_kernel(const float* __restrict__ deg,
                                                    float* __restrict__ dinv,
                                                    int* __restrict__ offs,
                                                    int* __restrict__ bsums, int n) {
    int i = blockIdx.x * 256 + threadIdx.x;
    int lane = threadIdx.x & 63;
    int wid = threadIdx.x >> 6;
    int cnt = 0;
    if (i < n) {
        float d = deg[i];
        dinv[i] = 1.0f / sqrtf(d);
        cnt = (int)d - 1;
    }
    int incl = wave_incl_scan(cnt, lane);
    __shared__ int ws[4];
    if (lane == 63) ws[wid] = incl;
    __syncthreads();
    if (threadIdx.x == 0) {
        int a = 0;
#pragma unroll
        for (int j = 0; j < 4; j++) { int t = ws[j]; ws[j] = a; a += t; }
        bsums[blockIdx.x] = a;
    }
    __syncthreads();
    int excl = incl - cnt + ws[wid];
    if (i < n) offs[i] = excl;
}

__global__ __launch_bounds__(512) void scan2_kernel(int* __restrict__ bsums, int nblk) {
    int lane = threadIdx.x & 63;
    int wid = threadIdx.x >> 6;
    int v = (threadIdx.x < nblk) ? bsums[threadIdx.x] : 0;
    int incl = wave_incl_scan(v, lane);
    __shared__ int ws[8];
    if (lane == 63) ws[wid] = incl;
    __syncthreads();
    if (threadIdx.x == 0) {
        int a = 0;
#pragma unroll
        for (int j = 0; j < 8; j++) { int t = ws[j]; ws[j] = a; a += t; }
    }
    __syncthreads();
    int excl = incl - v + ws[wid];
    if (threadIdx.x < nblk) bsums[threadIdx.x] = excl;
}

__global__ void scan3_kernel(int* __restrict__ offs, const int* __restrict__ bsums,
                             int* __restrict__ cursor, int n) {
    int i = blockIdx.x * 256 + threadIdx.x;
    if (i < n) {
        int o = offs[i] + bsums[i >> 8];
        offs[i] = o;
        cursor[i] = o;
    }
}

__global__ void fill_kernel(const int* __restrict__ row, const int* __restrict__ col,
                            int* __restrict__ cursor, int* __restrict__ csr, int E) {
    int e = blockIdx.x * 256 + threadIdx.x;
    if (e < E) {
        int c = col[e];
        int pos = atomicAdd(&cursor[c], 1);
        csr[pos] = row[e];
    }
}

// ---- transpose x[N][64] -> xt[8][N][8], pre-scaled by dinv[node] ----
__global__ __launch_bounds__(256) void transpose_scale_kernel(const float* __restrict__ x,
                                                              const float* __restrict__ dinv,
                                                              float* __restrict__ xt, int N) {
    int t = threadIdx.x;
    int c = t & 7;          // chunk
    int nl = t >> 3;        // local node (32 per block)
    int node = blockIdx.x * 32 + nl;
    if (node >= N) return;
    float dv = dinv[node];
    float4 v0 = *(const float4*)(x + (size_t)node * 64 + c * 8);
    float4 v1 = *(const float4*)(x + (size_t)node * 64 + c * 8 + 4);
    v0.x *= dv; v0.y *= dv; v0.z *= dv; v0.w *= dv;
    v1.x *= dv; v1.y *= dv; v1.z *= dv; v1.w *= dv;
    float* dst = xt + ((size_t)c * N + node) * 8;
    *(float4*)dst = v0;
    *(float4*)(dst + 4) = v1;
}

// ---- chunked aggregation ----
// Ut[chunk][node][8] already scaled by dinv[src].
// H[node][D] (row-major) = dinv[node] * (Ut self + sum in-edges) (+ bias)
// One block = 256 nodes x ONE chunk; chunk -> XCD via blockIdx%8.
template <bool STATS, bool BIAS>
__global__ __launch_bounds__(256) void agg_chunk_kernel(const float* __restrict__ Ut,
                                                        const int* __restrict__ csr,
                                                        const int* __restrict__ offs,
                                                        const float* __restrict__ deg,
                                                        const float* __restrict__ dinv,
                                                        const float* __restrict__ bias,
                                                        float* __restrict__ H,
                                                        double* __restrict__ stats,
                                                        int N, int D, int nodeblks, int nchunk) {
    int chunk, nb;
    if (nchunk == 8) {
        chunk = blockIdx.x & 7;
        nb = blockIdx.x >> 3;
    } else {  // 16 chunks: two grid halves, each XCD holds one chunk at a time
        int g8 = nodeblks << 3;
        int half = (blockIdx.x >= g8) ? 1 : 0;
        int rem = blockIdx.x - half * g8;
        chunk = (rem & 7) + (half << 3);
        nb = rem >> 3;
    }
    int node = nb * 256 + threadIdx.x;
    bool act = node < N;
    const float* __restrict__ Uc = Ut + (size_t)chunk * N * 8;

    float4 a0 = make_float4(0.f, 0.f, 0.f, 0.f), a1 = a0, c0 = a0, c1 = a0;
    int start = 0, cnt = 0;
    float dvi = 0.f;
    if (act) {
        start = offs[node];
        cnt = (int)deg[node] - 1;
        dvi = dinv[node];
        const float4* sp = (const float4*)(Uc + (size_t)node * 8);
        a0 = sp[0];
        a1 = sp[1];
    }
    int j = 0;
    for (; j + 2 <= cnt; j += 2) {
        int s0 = csr[start + j];
        int s1 = csr[start + j + 1];
        const float4* p0 = (const float4*)(Uc + (size_t)s0 * 8);
        const float4* p1 = (const float4*)(Uc + (size_t)s1 * 8);
        float4 v0 = p0[0], v1 = p0[1], w0 = p1[0], w1 = p1[1];
        a0.x += v0.x; a0.y += v0.y; a0.z += v0.z; a0.w += v0.w;
        a1.x += v1.x; a1.y += v1.y; a1.z += v1.z; a1.w += v1.w;
        c0.x += w0.x; c0.y += w0.y; c0.z += w0.z; c0.w += w0.w;
        c1.x += w1.x; c1.y += w1.y; c1.z += w1.z; c1.w += w1.w;
    }
    if (j < cnt) {
        int s0 = csr[start + j];
        const float4* p0 = (const float4*)(Uc + (size_t)s0 * 8);
        float4 v0 = p0[0], v1 = p0[1];
        a0.x += v0.x; a0.y += v0.y; a0.z += v0.z; a0.w += v0.w;
        a1.x += v1.x; a1.y += v1.y; a1.z += v1.z; a1.w += v1.w;
    }
    a0.x += c0.x; a0.y += c0.y; a0.z += c0.z; a0.w += c0.w;
    a1.x += c1.x; a1.y += c1.y; a1.z += c1.z; a1.w += c1.w;

    float h[8];
    h[0] = a0.x * dvi; h[1] = a0.y * dvi; h[2] = a0.z * dvi; h[3] = a0.w * dvi;
    h[4] = a1.x * dvi; h[5] = a1.y * dvi; h[6] = a1.z * dvi; h[7] = a1.w * dvi;
    if (BIAS) {
#pragma unroll
        for (int c = 0; c < 8; c++) h[c] += bias[chunk * 8 + c];
    }
    if (act) {
        float* dst = H + (size_t)node * D + chunk * 8;
        *(float4*)dst = make_float4(h[0], h[1], h[2], h[3]);
        *(float4*)(dst + 4) = make_float4(h[4], h[5], h[6], h[7]);
    } else {
#pragma unroll
        for (int c = 0; c < 8; c++) h[c] = 0.f;  // no stats contribution
    }

    if (STATS) {
        float s[8], q[8];
#pragma unroll
        for (int c = 0; c < 8; c++) { s[c] = h[c]; q[c] = h[c] * h[c]; }
#pragma unroll
        for (int st = 1; st < 64; st <<= 1) {
#pragma unroll
            for (int c = 0; c < 8; c++) {
                s[c] += __shfl_xor(s[c], st, 64);
                q[c] += __shfl_xor(q[c], st, 64);
            }
        }
        __shared__ float ps[4][8], pq[4][8];
        int wid = threadIdx.x >> 6;
        int lane = threadIdx.x & 63;
        if (lane == 0) {
#pragma unroll
            for (int c = 0; c < 8; c++) { ps[wid][c] = s[c]; pq[wid][c] = q[c]; }
        }
        __syncthreads();
        if (threadIdx.x < 8) {
            int c = threadIdx.x;
            float t = ps[0][c] + ps[1][c] + ps[2][c] + ps[3][c];
            atomicAdd(&stats[chunk * 8 + c], (double)t);
        } else if (threadIdx.x < 16) {
            int c = threadIdx.x - 8;
            float t = pq[0][c] + pq[1][c] + pq[2][c] + pq[3][c];
            atomicAdd(&stats[D + chunk * 8 + c], (double)t);
        }
    }
}

// ---- register-blocked GEMM ----
// BNIN: scale/shift+GELU on input staging. CHUNKED: write Ut[chunk][node][8].
// STATS: fused per-channel sum/sumsq (on final written values).
template <int DIN, int DOUT, bool BNIN, bool BIAS, bool DINVOUT, bool CHUNKED, bool STATS>
__global__ __launch_bounds__(256) void gemm_kernel(const float* __restrict__ Hin,
                                                   const float* __restrict__ W,
                                                   const float* __restrict__ scale,
                                                   const float* __restrict__ shift,
                                                   const float* __restrict__ bias,
                                                   const float* __restrict__ dinv,
                                                   float* __restrict__ Out,
                                                   double* __restrict__ stats, int n) {
    constexpr int BNODES = 64;
    constexpr int KT = 32;
    constexpr int HP = DIN + 4;
    constexpr int VC = DOUT / 16;      // 8 (DOUT=128) or 4 (DOUT=64)
    constexpr int C4 = VC / 4;
    __shared__ float Hs[BNODES * HP];
    __shared__ float Ws[KT * DOUT];
    __shared__ float ps[STATS ? 4 : 1][16][VC];
    __shared__ float pq[STATS ? 4 : 1][16][VC];

    int node0 = blockIdx.x * BNODES;
    int nv = n - node0;
    if (nv > BNODES) nv = BNODES;
    int cg = threadIdx.x & 15;
    int ng = threadIdx.x >> 4;

    constexpr int F4 = BNODES * (DIN / 4);
    for (int f = threadIdx.x; f < F4; f += 256) {
        int nn = f / (DIN / 4);
        int k4 = f - nn * (DIN / 4);
        float4 v = make_float4(0.f, 0.f, 0.f, 0.f);
        if (nn < nv)
            v = *(const float4*)(Hin + (size_t)(node0 + nn) * DIN + k4 * 4);
        if (BNIN) {
            float4 sc = *(const float4*)(scale + k4 * 4);
            float4 sh = *(const float4*)(shift + k4 * 4);
            v.x = gelu_f(fmaf(v.x, sc.x, sh.x));
            v.y = gelu_f(fmaf(v.y, sc.y, sh.y));
            v.z = gelu_f(fmaf(v.z, sc.z, sh.z));
            v.w = gelu_f(fmaf(v.w, sc.w, sh.w));
        }
        *(float4*)(Hs + nn * HP + k4 * 4) = v;
    }

    float acc[4][VC];
#pragma unroll
    for (int i = 0; i < 4; i++)
#pragma unroll
        for (int c = 0; c < VC; c++) acc[i][c] = 0.0f;

    for (int kb = 0; kb < DIN; kb += KT) {
        __syncthreads();
        for (int f = threadIdx.x; f < KT * DOUT / 4; f += 256)
            *(float4*)(Ws + f * 4) = *(const float4*)(W + (size_t)kb * DOUT + f * 4);
        __syncthreads();
#pragma unroll
        for (int kk = 0; kk < KT; kk++) {
            float h[4];
#pragma unroll
            for (int i = 0; i < 4; i++)
                h[i] = Hs[(ng * 4 + i) * HP + kb + kk];
            float w[VC];
#pragma unroll
            for (int c = 0; c < C4; c++) {
                float4 w4 = *(const float4*)(Ws + kk * DOUT + cg * VC + c * 4);
                w[c * 4 + 0] = w4.x; w[c * 4 + 1] = w4.y;
                w[c * 4 + 2] = w4.z; w[c * 4 + 3] = w4.w;
            }
#pragma unroll
            for (int i = 0; i < 4; i++)
#pragma unroll
                for (int c = 0; c < VC; c++)
                    acc[i][c] = fmaf(h[i], w[c], acc[i][c]);
        }
    }

    // epilogue: finalize, write, optional stats
    float fin[4][VC];
#pragma unroll
    for (int i = 0; i < 4; i++) {
        int nn = ng * 4 + i;
        bool valid = nn < nv;
        int node = node0 + nn;
        float dv = 1.0f;
        if (DINVOUT && valid) dv = dinv[node];
#pragma unroll
        for (int c = 0; c < VC; c++) {
            float f = acc[i][c] * dv;
            if (BIAS) f += bias[cg * VC + c];
            fin[i][c] = valid ? f : 0.f;
        }
        if (valid) {
            if (CHUNKED) {
                if (VC == 8) {
                    float* dst = Out + ((size_t)cg * n + node) * 8;
                    *(float4*)dst = make_float4(fin[i][0], fin[i][1], fin[i][2], fin[i][3]);
                    *(float4*)(dst + 4) = make_float4(fin[i][4], fin[i][5], fin[i][6], fin[i][7]);
                } else {  // VC == 4
                    float* dst = Out + ((size_t)(cg >> 1) * n + node) * 8 + (cg & 1) * 4;
                    *(float4*)dst = make_float4(fin[i][0], fin[i][1], fin[i][2], fin[i][3]);
                }
            } else {
#pragma unroll
                for (int c = 0; c < C4; c++)
                    *(float4*)(Out + (size_t)node * DOUT + cg * VC + c * 4) =
                        make_float4(fin[i][c * 4 + 0], fin[i][c * 4 + 1],
                                    fin[i][c * 4 + 2], fin[i][c * 4 + 3]);
            }
        }
    }

    if (STATS) {
        float s[VC], q[VC];
#pragma unroll
        for (int c = 0; c < VC; c++) {
            s[c] = fin[0][c] + fin[1][c] + fin[2][c] + fin[3][c];
            q[c] = fin[0][c] * fin[0][c] + fin[1][c] * fin[1][c] +
                   fin[2][c] * fin[2][c] + fin[3][c] * fin[3][c];
        }
#pragma unroll
        for (int st = 16; st < 64; st <<= 1) {
#pragma unroll
            for (int c = 0; c < VC; c++) {
                s[c] += __shfl_xor(s[c], st, 64);
                q[c] += __shfl_xor(q[c], st, 64);
            }
        }
        int wid = threadIdx.x >> 6;
        int lane = threadIdx.x & 63;
        if (lane < 16) {
#pragma unroll
            for (int c = 0; c < VC; c++) { ps[wid][lane][c] = s[c]; pq[wid][lane][c] = q[c]; }
        }
        __syncthreads();
        if (threadIdx.x < DOUT) {
            int col = threadIdx.x;
            int cgi = col / VC, ci = col % VC;
            float t = ps[0][cgi][ci] + ps[1][cgi][ci] + ps[2][cgi][ci] + ps[3][cgi][ci];
            float t2 = pq[0][cgi][ci] + pq[1][cgi][ci] + pq[2][cgi][ci] + pq[3][cgi][ci];
            atomicAdd(&stats[col], (double)t);
            atomicAdd(&stats[DOUT + col], (double)t2);
        }
    }
}

// ---- stats sums -> per-channel scale/shift floats ----
template <int D>
__global__ void finalize_kernel(const double* __restrict__ stats,
                                const float* __restrict__ g, const float* __restrict__ be,
                                float* __restrict__ scale, float* __restrict__ shift, int n) {
    int c = threadIdx.x;
    if (c < D) {
        double mu = stats[c] / n;
        double var = stats[c + D] / n - mu * mu;
        double inv = 1.0 / sqrt(var + 1e-5);
        double sc = (double)g[c] * inv;
        scale[c] = (float)sc;
        shift[c] = (float)((double)be[c] - mu * sc);
    }
}

// ---- layer-3: BN normalize + GELU + residual(x) + mean-pool accumulate ----
__global__ __launch_bounds__(256) void norm_pool_kernel(const float* __restrict__ X3,
                                                        const float* __restrict__ x0,
                                                        const double* __restrict__ stats,
                                                        const float* __restrict__ gw,
                                                        const float* __restrict__ be,
                                                        double* __restrict__ pool, int n) {
    constexpr int D = 64;
    constexpr int RPB = 4;
    int c = threadIdx.x % D;
    double mu = stats[c] / n;
    double var = stats[c + D] / n - mu * mu;
    double inv = 1.0 / sqrt(var + 1e-5);
    float scale = (float)((double)gw[c] * inv);
    float shift = (float)((double)be[c] - mu * (double)gw[c] * inv);
    int r0 = threadIdx.x / D;
    int rowsPerGrid = gridDim.x * RPB;
    double s = 0.0;
    for (int r = blockIdx.x * RPB + r0; r < n; r += rowsPerGrid) {
        size_t idx = (size_t)r * D + c;
        float t = fmaf(X3[idx], scale, shift);
        float res = x0[idx] + gelu_f(t);
        s += res;
    }
    __shared__ double sh[256];
    sh[threadIdx.x] = s;
    __syncthreads();
    if (threadIdx.x < D) {
#pragma unroll
        for (int j = 1; j < RPB; j++) s += sh[threadIdx.x + j * D];
        atomicAdd(&pool[c], s);
    }
}

// ---- head MLP: 64 ->128 ->64 ->32 ->1, single block ----
__global__ __launch_bounds__(128) void mlp_kernel(const double* __restrict__ pool,
                                                  const float* __restrict__ w1, const float* __restrict__ b1,
                                                  const float* __restrict__ w2, const float* __restrict__ b2,
                                                  const float* __restrict__ w3, const float* __restrict__ b3,
                                                  const float* __restrict__ w4, const float* __restrict__ b4,
                                                  float* __restrict__ out, int n) {
    __shared__ float v0[64], h1[128], h2[64], h3[32];
    int t = threadIdx.x;
    if (t < 64) v0[t] = (float)(pool[t] / (double)n);
    __syncthreads();
    if (t < 128) {
        float a = b1[t];
        for (int k = 0; k < 64; k++) a = fmaf(v0[k], w1[k * 128 + t], a);
        h1[t] = gelu_f(a);
    }
    __syncthreads();
    if (t < 64) {
        float a = b2[t];
        for (int k = 0; k < 128; k++) a = fmaf(h1[k], w2[k * 64 + t], a);
        h2[t] = gelu_f(a);
    }
    __syncthreads();
    if (t < 32) {
        float a = b3[t];
        for (int k = 0; k < 64; k++) a = fmaf(h2[k], w3[k * 32 + t], a);
        h3[t] = gelu_f(a);
    }
    __syncthreads();
    if (t == 0) {
        float a = b4[0];
        for (int k = 0; k < 32; k++) a = fmaf(h3[k], w4[k], a);
        out[0] = a;
    }
}

extern "C" void kernel_launch(void* const* d_in, const int* in_sizes, int n_in,
                              void* d_out, int out_size, void* d_ws, size_t ws_size,
                              hipStream_t stream) {
    const float* x    = (const float*)d_in[0];
    const int*   ei   = (const int*)d_in[1];
    const float* W1   = (const float*)d_in[2];
    const float* b1   = (const float*)d_in[3];
    const float* g1   = (const float*)d_in[4];
    const float* be1  = (const float*)d_in[5];
    const float* W2   = (const float*)d_in[6];
    const float* b2   = (const float*)d_in[7];
    const float* g2   = (const float*)d_in[8];
    const float* be2  = (const float*)d_in[9];
    const float* W3   = (const float*)d_in[10];
    const float* b3   = (const float*)d_in[11];
    const float* g3   = (const float*)d_in[12];
    const float* be3  = (const float*)d_in[13];
    const float* fc1w = (const float*)d_in[14];
    const float* fc1b = (const float*)d_in[15];
    const float* fc2w = (const float*)d_in[16];
    const float* fc2b = (const float*)d_in[17];
    const float* fc3w = (const float*)d_in[18];
    const float* fc3b = (const float*)d_in[19];
    const float* fc4w = (const float*)d_in[20];
    const float* fc4b = (const float*)d_in[21];

    const int N = in_sizes[0] / 64;
    const int E = in_sizes[1] / 2;
    const int* e_row = ei;       // source
    const int* e_col = ei + E;   // target (aggregation index)

    // ---- workspace layout (aliased; ~110.5 MB total) ----
    char* ws = (char*)d_ws;
    size_t off = 0;
    double* stats1 = (double*)(ws + off); off += 256 * sizeof(double);
    double* stats2 = (double*)(ws + off); off += 256 * sizeof(double);
    double* stats3 = (double*)(ws + off); off += 256 * sizeof(double);
    double* pool   = (double*)(ws + off); off += 64 * sizeof(double);
    float* scale1 = (float*)(ws + off); off += 128 * sizeof(float);
    float* shift1 = (float*)(ws + off); off += 128 * sizeof(float);
    float* scale2 = (float*)(ws + off); off += 128 * sizeof(float);
    float* shift2 = (float*)(ws + off); off += 128 * sizeof(float);
    float* deg   = (float*)(ws + off); off += (size_t)N * sizeof(float);
    float* dinv  = (float*)(ws + off); off += (size_t)N * sizeof(float);
    off = (off + 15) & ~(size_t)15;
    int* offs    = (int*)(ws + off); off += (size_t)N * sizeof(int);
    int* cursor  = (int*)(ws + off); off += (size_t)N * sizeof(int);
    int* bsums   = (int*)(ws + off); off += 512 * sizeof(int);
    int* csr     = (int*)(ws + off); off += (size_t)E * sizeof(int);
    off = (off + 255) & ~(size_t)255;
    float* Ut    = (float*)(ws + off); off += (size_t)N * 128 * sizeof(float);  // chunked
    float* H     = (float*)(ws + off); off += (size_t)N * 128 * sizeof(float);  // row-major
    // aliases: xt = H (dead once agg1 done, before gemm1 writes H1)
    //          A1 = Ut head [N][64] row-major (dead before gemm2 writes Ut)
    float* xt = H;
    float* A1 = Ut;

    const int nb256 = (N + 255) / 256;
    const int ebl = (E + 255) / 256;
    const int nodeblks = nb256;

    init_kernel<<<nb256, 256, 0, stream>>>(deg, stats1, N, 832);
    degree_kernel<<<ebl, 256, 0, stream>>>(e_col, deg, E);
    scan1_kernel<<<nb256, 256, 0, stream>>>(deg, dinv, offs, bsums, N);
    scan2_kernel<<<1, 512, 0, stream>>>(bsums, nb256);
    scan3_kernel<<<nb256, 256, 0, stream>>>(offs, bsums, cursor, N);
    fill_kernel<<<ebl, 256, 0, stream>>>(e_row, e_col, cursor, csr, E);

    // Layer 1: transpose+prescale x -> xt; chunked agg -> A1; GEMM(+b1,+stats1) -> H1
    transpose_scale_kernel<<<(N + 31) / 32, 256, 0, stream>>>(x, dinv, xt, N);
    agg_chunk_kernel<false, false><<<8 * nodeblks, 256, 0, stream>>>(
        xt, csr, offs, deg, dinv, nullptr, A1, nullptr, N, 64, nodeblks, 8);
    gemm_kernel<64, 128, false, true, false, false, true><<<(N + 63) / 64, 256, 0, stream>>>(
        A1, W1, nullptr, nullptr, b1, dinv, H, stats1, N);
    finalize_kernel<128><<<1, 128, 0, stream>>>(stats1, g1, be1, scale1, shift1, N);

    // Layer 2: GEMM (BN1+GELU fused, dinv-scaled, chunked out) -> Ut; agg(+b2,+stats2) -> H2
    gemm_kernel<128, 128, true, false, true, true, false><<<(N + 63) / 64, 256, 0, stream>>>(
        H, W2, scale1, shift1, nullptr, dinv, Ut, nullptr, N);
    agg_chunk_kernel<true, true><<<16 * nodeblks, 256, 0, stream>>>(
        Ut, csr, offs, deg, dinv, b2, H, stats2, N, 128, nodeblks, 16);
    finalize_kernel<128><<<1, 128, 0, stream>>>(stats2, g2, be2, scale2, shift2, N);

    // Layer 3: GEMM (BN2+GELU fused, chunked out 64) -> Ut[0..8); agg(+b3,+stats3) -> H3
    gemm_kernel<128, 64, true, false, true, true, false><<<(N + 63) / 64, 256, 0, stream>>>(
        H, W3, scale2, shift2, nullptr, dinv, Ut, nullptr, N);
    agg_chunk_kernel<true, true><<<8 * nodeblks, 256, 0, stream>>>(
        Ut, csr, offs, deg, dinv, b3, H, stats3, N, 64, nodeblks, 8);

    // Epilogue: BN3+GELU+residual+meanpool, then head MLP
    norm_pool_kernel<<<1024, 256, 0, stream>>>(H, x, stats3, g3, be3, pool, N);
    mlp_kernel<<<1, 128, 0, stream>>>(pool, fc1w, fc1b, fc2w, fc2b, fc3w, fc3b,
                                      fc4w, fc4b, (float*)d_out, N);
}

// Round 4
// 725.633 us; speedup vs baseline: 1.3613x; 1.3613x over previous
//
#include <hip/hip_runtime.h>
#include <hip/hip_bf16.h>
#include <hip/hip_fp16.h>
#include <math.h>

// GNN: 3-layer GCN + BN + GELU + residual + meanpool + MLP -> scalar.
// R4: revert agg to row-major full-row gathers (R3 chunking was a 2.2x LOSS:
// 32B granules wasted 128B lines). New lever: gather tables stored fp16
// (halves gather bytes AND table size -> better L2 hit rate), fp32 accumulate.
// BN stats stay fused in agg/gemm epilogues; BN+GELU fused in GEMM staging.

__device__ __forceinline__ float gelu_f(float x) {
    return 0.5f * x * (1.0f + erff(x * 0.7071067811865476f));
}

__device__ __forceinline__ int wave_incl_scan(int v, int lane) {
#pragma unroll
    for (int off = 1; off < 64; off <<= 1) {
        int t = __shfl_up(v, (unsigned)off, 64);
        if (lane >= off) v += t;
    }
    return v;
}

__device__ __forceinline__ void load8h(const __half* __restrict__ p, float* f) {
    uint4 u = *(const uint4*)p;                 // 8 halfs, 16B
    const __half2* h2p = (const __half2*)&u;
#pragma unroll
    for (int i = 0; i < 4; i++) {
        float2 t = __half22float2(h2p[i]);
        f[2 * i] = t.x;
        f[2 * i + 1] = t.y;
    }
}

// ---- init: deg = 1.0 (self loop), zero double accumulators ----
__global__ void init_kernel(float* __restrict__ deg, double* __restrict__ dbls,
                            int n, int ndbl) {
    int i = blockIdx.x * 256 + threadIdx.x;
    if (i < n) deg[i] = 1.0f;
    if (i < ndbl) dbls[i] = 0.0;
}

__global__ void degree_kernel(const int* __restrict__ col, float* __restrict__ deg, int E) {
    int e = blockIdx.x * 256 + threadIdx.x;
    if (e < E) atomicAdd(&deg[col[e]], 1.0f);
}

__global__ __launch_bounds__(256) void scan1_kernel(const float* __restrict__ deg,
                                                    float* __restrict__ dinv,
                                                    int* __restrict__ offs,
                                                    int* __restrict__ bsums, int n) {
    int i = blockIdx.x * 256 + threadIdx.x;
    int lane = threadIdx.x & 63;
    int wid = threadIdx.x >> 6;
    int cnt = 0;
    if (i < n) {
        float d = deg[i];
        dinv[i] = 1.0f / sqrtf(d);
        cnt = (int)d - 1;
    }
    int incl = wave_incl_scan(cnt, lane);
    __shared__ int ws[4];
    if (lane == 63) ws[wid] = incl;
    __syncthreads();
    if (threadIdx.x == 0) {
        int a = 0;
#pragma unroll
        for (int j = 0; j < 4; j++) { int t = ws[j]; ws[j] = a; a += t; }
        bsums[blockIdx.x] = a;
    }
    __syncthreads();
    int excl = incl - cnt + ws[wid];
    if (i < n) offs[i] = excl;
}

__global__ __launch_bounds__(512) void scan2_kernel(int* __restrict__ bsums, int nblk) {
    int lane = threadIdx.x & 63;
    int wid = threadIdx.x >> 6;
    int v = (threadIdx.x < nblk) ? bsums[threadIdx.x] : 0;
    int incl = wave_incl_scan(v, lane);
    __shared__ int ws[8];
    if (lane == 63) ws[wid] = incl;
    __syncthreads();
    if (threadIdx.x == 0) {
        int a = 0;
#pragma unroll
        for (int j = 0; j < 8; j++) { int t = ws[j]; ws[j] = a; a += t; }
    }
    __syncthreads();
    int excl = incl - v + ws[wid];
    if (threadIdx.x < nblk) bsums[threadIdx.x] = excl;
}

__global__ void scan3_kernel(int* __restrict__ offs, const int* __restrict__ bsums,
                             int* __restrict__ cursor, int n) {
    int i = blockIdx.x * 256 + threadIdx.x;
    if (i < n) {
        int o = offs[i] + bsums[i >> 8];
        offs[i] = o;
        cursor[i] = o;
    }
}

__global__ void fill_kernel(const int* __restrict__ row, const int* __restrict__ col,
                            int* __restrict__ cursor, int* __restrict__ csr, int E) {
    int e = blockIdx.x * 256 + threadIdx.x;
    if (e < E) {
        int c = col[e];
        int pos = atomicAdd(&cursor[c], 1);
        csr[pos] = row[e];
    }
}

// ---- convert x[N][64] fp32 -> xh[N][64] fp16, scaled by dinv[node] ----
__global__ __launch_bounds__(256) void halfconv_kernel(const float* __restrict__ x,
                                                       const float* __restrict__ dinv,
                                                       __half* __restrict__ xh, int N) {
    int t = blockIdx.x * 256 + threadIdx.x;   // one 8-float chunk per thread
    if (t >= N * 8) return;
    int node = t >> 3;
    float dv = dinv[node];
    const float4* p = (const float4*)(x + (size_t)t * 8);
    float4 a = p[0], b = p[1];
    __half2 h[4];
    h[0] = __floats2half2_rn(a.x * dv, a.y * dv);
    h[1] = __floats2half2_rn(a.z * dv, a.w * dv);
    h[2] = __floats2half2_rn(b.x * dv, b.y * dv);
    h[3] = __floats2half2_rn(b.z * dv, b.w * dv);
    *(uint4*)(xh + (size_t)t * 8) = *(uint4*)h;
}

// ---- aggregation: H[i][D] = dinv_i*(Ut[i] + sum in-edge Ut[src]) (+bias) ----
// Ut is fp16 row-major, pre-scaled by dinv[src]. fp32 accumulate.
// GPN = D/8 threads per node, each owns 8 channels (16B gathers).
template <int D, bool STATS, bool BIAS>
__global__ __launch_bounds__(256) void agg_kernel(const __half* __restrict__ Ut,
                                                  const int* __restrict__ csr,
                                                  const int* __restrict__ offs,
                                                  const float* __restrict__ deg,
                                                  const float* __restrict__ dinv,
                                                  const float* __restrict__ bias,
                                                  float* __restrict__ H,
                                                  double* __restrict__ stats, int n) {
    constexpr int GPN = D / 8;
    constexpr int NPB = 256 / GPN;
    int g = threadIdx.x / GPN;
    int cl = threadIdx.x % GPN;
    int node = blockIdx.x * NPB + g;
    bool act = node < n;

    float a[8], b[8];
#pragma unroll
    for (int c = 0; c < 8; c++) { a[c] = 0.f; b[c] = 0.f; }

    int start = 0, cnt = 0;
    float dvi = 0.f;
    if (act) {
        start = offs[node];
        cnt = (int)deg[node] - 1;
        dvi = dinv[node];
        load8h(Ut + (size_t)node * D + cl * 8, a);   // self loop (pre-scaled)
    }
    int j = 0;
    for (; j + 2 <= cnt; j += 2) {
        int s0 = csr[start + j];
        int s1 = csr[start + j + 1];
        float f0[8], f1[8];
        load8h(Ut + (size_t)s0 * D + cl * 8, f0);
        load8h(Ut + (size_t)s1 * D + cl * 8, f1);
#pragma unroll
        for (int c = 0; c < 8; c++) { a[c] += f0[c]; b[c] += f1[c]; }
    }
    if (j < cnt) {
        int s0 = csr[start + j];
        float f0[8];
        load8h(Ut + (size_t)s0 * D + cl * 8, f0);
#pragma unroll
        for (int c = 0; c < 8; c++) a[c] += f0[c];
    }

    float h[8];
#pragma unroll
    for (int c = 0; c < 8; c++) h[c] = (a[c] + b[c]) * dvi;
    if (BIAS) {
#pragma unroll
        for (int c = 0; c < 8; c++) h[c] += bias[cl * 8 + c];
    }
    if (act) {
        float* dst = H + (size_t)node * D + cl * 8;
        *(float4*)dst = make_float4(h[0], h[1], h[2], h[3]);
        *(float4*)(dst + 4) = make_float4(h[4], h[5], h[6], h[7]);
    } else {
#pragma unroll
        for (int c = 0; c < 8; c++) h[c] = 0.f;   // no stats contribution
    }

    if (STATS) {
        float s[8], q[8];
#pragma unroll
        for (int c = 0; c < 8; c++) { s[c] = h[c]; q[c] = h[c] * h[c]; }
#pragma unroll
        for (int m = GPN; m < 64; m <<= 1) {
#pragma unroll
            for (int c = 0; c < 8; c++) {
                s[c] += __shfl_xor(s[c], m, 64);
                q[c] += __shfl_xor(q[c], m, 64);
            }
        }
        __shared__ float ps[4][GPN][8], pq[4][GPN][8];
        int wid = threadIdx.x >> 6;
        int lane = threadIdx.x & 63;
        if (lane < GPN) {
#pragma unroll
            for (int c = 0; c < 8; c++) { ps[wid][lane][c] = s[c]; pq[wid][lane][c] = q[c]; }
        }
        __syncthreads();
        if (threadIdx.x < D) {
            int cgi = threadIdx.x >> 3, ci = threadIdx.x & 7;
            float t1 = ps[0][cgi][ci] + ps[1][cgi][ci] + ps[2][cgi][ci] + ps[3][cgi][ci];
            float t2 = pq[0][cgi][ci] + pq[1][cgi][ci] + pq[2][cgi][ci] + pq[3][cgi][ci];
            atomicAdd(&stats[threadIdx.x], (double)t1);
            atomicAdd(&stats[D + threadIdx.x], (double)t2);
        }
    }
}

// ---- register-blocked GEMM ----
// BNIN: scale/shift+GELU on input staging. HALFOUT: write fp16 row-major.
// STATS: fused per-channel sum/sumsq on written (fp32) values.
template <int DIN, int DOUT, bool BNIN, bool BIAS, bool DINVOUT, bool HALFOUT, bool STATS>
__global__ __launch_bounds__(256) void gemm_kernel(const float* __restrict__ Hin,
                                                   const float* __restrict__ W,
                                                   const float* __restrict__ scale,
                                                   const float* __restrict__ shift,
                                                   const float* __restrict__ bias,
                                                   const float* __restrict__ dinv,
                                                   float* __restrict__ Out,
                                                   double* __restrict__ stats, int n) {
    constexpr int BNODES = 64;
    constexpr int KT = 32;
    constexpr int HP = DIN + 4;
    constexpr int VC = DOUT / 16;      // 8 (DOUT=128) or 4 (DOUT=64)
    constexpr int C4 = VC / 4;
    __shared__ float Hs[BNODES * HP];
    __shared__ float Ws[KT * DOUT];
    __shared__ float ps[STATS ? 4 : 1][16][VC];
    __shared__ float pq[STATS ? 4 : 1][16][VC];

    int node0 = blockIdx.x * BNODES;
    int nv = n - node0;
    if (nv > BNODES) nv = BNODES;
    int cg = threadIdx.x & 15;
    int ng = threadIdx.x >> 4;

    constexpr int F4 = BNODES * (DIN / 4);
    for (int f = threadIdx.x; f < F4; f += 256) {
        int nn = f / (DIN / 4);
        int k4 = f - nn * (DIN / 4);
        float4 v = make_float4(0.f, 0.f, 0.f, 0.f);
        if (nn < nv)
            v = *(const float4*)(Hin + (size_t)(node0 + nn) * DIN + k4 * 4);
        if (BNIN) {
            float4 sc = *(const float4*)(scale + k4 * 4);
            float4 sh = *(const float4*)(shift + k4 * 4);
            v.x = gelu_f(fmaf(v.x, sc.x, sh.x));
            v.y = gelu_f(fmaf(v.y, sc.y, sh.y));
            v.z = gelu_f(fmaf(v.z, sc.z, sh.z));
            v.w = gelu_f(fmaf(v.w, sc.w, sh.w));
        }
        *(float4*)(Hs + nn * HP + k4 * 4) = v;
    }

    float acc[4][VC];
#pragma unroll
    for (int i = 0; i < 4; i++)
#pragma unroll
        for (int c = 0; c < VC; c++) acc[i][c] = 0.0f;

    for (int kb = 0; kb < DIN; kb += KT) {
        __syncthreads();
        for (int f = threadIdx.x; f < KT * DOUT / 4; f += 256)
            *(float4*)(Ws + f * 4) = *(const float4*)(W + (size_t)kb * DOUT + f * 4);
        __syncthreads();
#pragma unroll
        for (int kk = 0; kk < KT; kk++) {
            float h[4];
#pragma unroll
            for (int i = 0; i < 4; i++)
                h[i] = Hs[(ng * 4 + i) * HP + kb + kk];
            float w[VC];
#pragma unroll
            for (int c = 0; c < C4; c++) {
                float4 w4 = *(const float4*)(Ws + kk * DOUT + cg * VC + c * 4);
                w[c * 4 + 0] = w4.x; w[c * 4 + 1] = w4.y;
                w[c * 4 + 2] = w4.z; w[c * 4 + 3] = w4.w;
            }
#pragma unroll
            for (int i = 0; i < 4; i++)
#pragma unroll
                for (int c = 0; c < VC; c++)
                    acc[i][c] = fmaf(h[i], w[c], acc[i][c]);
        }
    }

    float fin[4][VC];
#pragma unroll
    for (int i = 0; i < 4; i++) {
        int nn = ng * 4 + i;
        bool valid = nn < nv;
        int node = node0 + nn;
        float dv = 1.0f;
        if (DINVOUT && valid) dv = dinv[node];
#pragma unroll
        for (int c = 0; c < VC; c++) {
            float f = acc[i][c] * dv;
            if (BIAS) f += bias[cg * VC + c];
            fin[i][c] = valid ? f : 0.f;
        }
        if (valid) {
            if (HALFOUT) {
                __half* hp = (__half*)Out + (size_t)node * DOUT + cg * VC;
                if (VC == 8) {
                    __half2 pk[4];
                    pk[0] = __floats2half2_rn(fin[i][0], fin[i][1]);
                    pk[1] = __floats2half2_rn(fin[i][2], fin[i][3]);
                    pk[2] = __floats2half2_rn(fin[i][4], fin[i][5]);
                    pk[3] = __floats2half2_rn(fin[i][6], fin[i][7]);
                    *(uint4*)hp = *(uint4*)pk;
                } else {
                    __half2 pk[2];
                    pk[0] = __floats2half2_rn(fin[i][0], fin[i][1]);
                    pk[1] = __floats2half2_rn(fin[i][2], fin[i][3]);
                    *(uint2*)hp = *(uint2*)pk;
                }
            } else {
#pragma unroll
                for (int c = 0; c < C4; c++)
                    *(float4*)(Out + (size_t)node * DOUT + cg * VC + c * 4) =
                        make_float4(fin[i][c * 4 + 0], fin[i][c * 4 + 1],
                                    fin[i][c * 4 + 2], fin[i][c * 4 + 3]);
            }
        }
    }

    if (STATS) {
        float s[VC], q[VC];
#pragma unroll
        for (int c = 0; c < VC; c++) {
            s[c] = fin[0][c] + fin[1][c] + fin[2][c] + fin[3][c];
            q[c] = fin[0][c] * fin[0][c] + fin[1][c] * fin[1][c] +
                   fin[2][c] * fin[2][c] + fin[3][c] * fin[3][c];
        }
#pragma unroll
        for (int st = 16; st < 64; st <<= 1) {
#pragma unroll
            for (int c = 0; c < VC; c++) {
                s[c] += __shfl_xor(s[c], st, 64);
                q[c] += __shfl_xor(q[c], st, 64);
            }
        }
        int wid = threadIdx.x >> 6;
        int lane = threadIdx.x & 63;
        if (lane < 16) {
#pragma unroll
            for (int c = 0; c < VC; c++) { ps[wid][lane][c] = s[c]; pq[wid][lane][c] = q[c]; }
        }
        __syncthreads();
        if (threadIdx.x < DOUT) {
            int col = threadIdx.x;
            int cgi = col / VC, ci = col % VC;
            float t = ps[0][cgi][ci] + ps[1][cgi][ci] + ps[2][cgi][ci] + ps[3][cgi][ci];
            float t2 = pq[0][cgi][ci] + pq[1][cgi][ci] + pq[2][cgi][ci] + pq[3][cgi][ci];
            atomicAdd(&stats[col], (double)t);
            atomicAdd(&stats[DOUT + col], (double)t2);
        }
    }
}

// ---- stats sums -> per-channel scale/shift floats ----
template <int D>
__global__ void finalize_kernel(const double* __restrict__ stats,
                                const float* __restrict__ g, const float* __restrict__ be,
                                float* __restrict__ scale, float* __restrict__ shift, int n) {
    int c = threadIdx.x;
    if (c < D) {
        double mu = stats[c] / n;
        double var = stats[c + D] / n - mu * mu;
        double inv = 1.0 / sqrt(var + 1e-5);
        double sc = (double)g[c] * inv;
        scale[c] = (float)sc;
        shift[c] = (float)((double)be[c] - mu * sc);
    }
}

// ---- layer-3: BN normalize + GELU + residual(x) + mean-pool accumulate ----
__global__ __launch_bounds__(256) void norm_pool_kernel(const float* __restrict__ X3,
                                                        const float* __restrict__ x0,
                                                        const double* __restrict__ stats,
                                                        const float* __restrict__ gw,
                                                        const float* __restrict__ be,
                                                        double* __restrict__ pool, int n) {
    constexpr int D = 64;
    constexpr int RPB = 4;
    int c = threadIdx.x % D;
    double mu = stats[c] / n;
    double var = stats[c + D] / n - mu * mu;
    double inv = 1.0 / sqrt(var + 1e-5);
    float scale = (float)((double)gw[c] * inv);
    float shift = (float)((double)be[c] - mu * (double)gw[c] * inv);
    int r0 = threadIdx.x / D;
    int rowsPerGrid = gridDim.x * RPB;
    double s = 0.0;
    for (int r = blockIdx.x * RPB + r0; r < n; r += rowsPerGrid) {
        size_t idx = (size_t)r * D + c;
        float t = fmaf(X3[idx], scale, shift);
        float res = x0[idx] + gelu_f(t);
        s += res;
    }
    __shared__ double sh[256];
    sh[threadIdx.x] = s;
    __syncthreads();
    if (threadIdx.x < D) {
#pragma unroll
        for (int j = 1; j < RPB; j++) s += sh[threadIdx.x + j * D];
        atomicAdd(&pool[c], s);
    }
}

// ---- head MLP: 64 ->128 ->64 ->32 ->1, single block ----
__global__ __launch_bounds__(128) void mlp_kernel(const double* __restrict__ pool,
                                                  const float* __restrict__ w1, const float* __restrict__ b1,
                                                  const float* __restrict__ w2, const float* __restrict__ b2,
                                                  const float* __restrict__ w3, const float* __restrict__ b3,
                                                  const float* __restrict__ w4, const float* __restrict__ b4,
                                                  float* __restrict__ out, int n) {
    __shared__ float v0[64], h1[128], h2[64], h3[32];
    int t = threadIdx.x;
    if (t < 64) v0[t] = (float)(pool[t] / (double)n);
    __syncthreads();
    if (t < 128) {
        float a = b1[t];
        for (int k = 0; k < 64; k++) a = fmaf(v0[k], w1[k * 128 + t], a);
        h1[t] = gelu_f(a);
    }
    __syncthreads();
    if (t < 64) {
        float a = b2[t];
        for (int k = 0; k < 128; k++) a = fmaf(h1[k], w2[k * 64 + t], a);
        h2[t] = gelu_f(a);
    }
    __syncthreads();
    if (t < 32) {
        float a = b3[t];
        for (int k = 0; k < 64; k++) a = fmaf(h2[k], w3[k * 32 + t], a);
        h3[t] = gelu_f(a);
    }
    __syncthreads();
    if (t == 0) {
        float a = b4[0];
        for (int k = 0; k < 32; k++) a = fmaf(h3[k], w4[k], a);
        out[0] = a;
    }
}

extern "C" void kernel_launch(void* const* d_in, const int* in_sizes, int n_in,
                              void* d_out, int out_size, void* d_ws, size_t ws_size,
                              hipStream_t stream) {
    const float* x    = (const float*)d_in[0];
    const int*   ei   = (const int*)d_in[1];
    const float* W1   = (const float*)d_in[2];
    const float* b1   = (const float*)d_in[3];
    const float* g1   = (const float*)d_in[4];
    const float* be1  = (const float*)d_in[5];
    const float* W2   = (const float*)d_in[6];
    const float* b2   = (const float*)d_in[7];
    const float* g2   = (const float*)d_in[8];
    const float* be2  = (const float*)d_in[9];
    const float* W3   = (const float*)d_in[10];
    const float* b3   = (const float*)d_in[11];
    const float* g3   = (const float*)d_in[12];
    const float* be3  = (const float*)d_in[13];
    const float* fc1w = (const float*)d_in[14];
    const float* fc1b = (const float*)d_in[15];
    const float* fc2w = (const float*)d_in[16];
    const float* fc2b = (const float*)d_in[17];
    const float* fc3w = (const float*)d_in[18];
    const float* fc3b = (const float*)d_in[19];
    const float* fc4w = (const float*)d_in[20];
    const float* fc4b = (const float*)d_in[21];

    const int N = in_sizes[0] / 64;
    const int E = in_sizes[1] / 2;
    const int* e_row = ei;       // source
    const int* e_col = ei + E;   // target (aggregation index)

    // ---- workspace layout (~110 MB) ----
    char* ws = (char*)d_ws;
    size_t off = 0;
    double* stats1 = (double*)(ws + off); off += 256 * sizeof(double);
    double* stats2 = (double*)(ws + off); off += 256 * sizeof(double);
    double* stats3 = (double*)(ws + off); off += 256 * sizeof(double);
    double* pool   = (double*)(ws + off); off += 64 * sizeof(double);
    float* scale1 = (float*)(ws + off); off += 128 * sizeof(float);
    float* shift1 = (float*)(ws + off); off += 128 * sizeof(float);
    float* scale2 = (float*)(ws + off); off += 128 * sizeof(float);
    float* shift2 = (float*)(ws + off); off += 128 * sizeof(float);
    float* deg   = (float*)(ws + off); off += (size_t)N * sizeof(float);
    float* dinv  = (float*)(ws + off); off += (size_t)N * sizeof(float);
    off = (off + 15) & ~(size_t)15;
    int* offs    = (int*)(ws + off); off += (size_t)N * sizeof(int);
    int* cursor  = (int*)(ws + off); off += (size_t)N * sizeof(int);
    int* bsums   = (int*)(ws + off); off += 512 * sizeof(int);
    int* csr     = (int*)(ws + off); off += (size_t)E * sizeof(int);
    off = (off + 255) & ~(size_t)255;
    __half* Ut   = (__half*)(ws + off); off += (size_t)N * 128 * sizeof(__half);  // fp16 gather table
    float* A1    = (float*)(ws + off);  off += (size_t)N * 64 * sizeof(float);    // agg1 out (fp32)
    float* H     = (float*)(ws + off);  off += (size_t)N * 128 * sizeof(float);   // fp32 row-major
    __half* xh   = Ut;  // alias: xh dead after agg1, before gemm2 writes Ut

    const int nb256 = (N + 255) / 256;
    const int ebl = (E + 255) / 256;

    init_kernel<<<nb256, 256, 0, stream>>>(deg, stats1, N, 832);
    degree_kernel<<<ebl, 256, 0, stream>>>(e_col, deg, E);
    scan1_kernel<<<nb256, 256, 0, stream>>>(deg, dinv, offs, bsums, N);
    scan2_kernel<<<1, 512, 0, stream>>>(bsums, nb256);
    scan3_kernel<<<nb256, 256, 0, stream>>>(offs, bsums, cursor, N);
    fill_kernel<<<ebl, 256, 0, stream>>>(e_row, e_col, cursor, csr, E);

    // Layer 1: x -> fp16 (xdinv-scaled); agg 64-dim -> A1; GEMM(+b1,+stats1) -> H1
    halfconv_kernel<<<(N * 8 + 255) / 256, 256, 0, stream>>>(x, dinv, xh, N);
    agg_kernel<64, false, false><<<(N + 31) / 32, 256, 0, stream>>>(
        xh, csr, offs, deg, dinv, nullptr, A1, nullptr, N);
    gemm_kernel<64, 128, false, true, false, false, true><<<(N + 63) / 64, 256, 0, stream>>>(
        A1, W1, nullptr, nullptr, b1, dinv, H, stats1, N);
    finalize_kernel<128><<<1, 128, 0, stream>>>(stats1, g1, be1, scale1, shift1, N);

    // Layer 2: GEMM (BN1+GELU fused, dinv-scaled, fp16 out) -> Ut; agg(+b2,+stats2) -> H2
    gemm_kernel<128, 128, true, false, true, true, false><<<(N + 63) / 64, 256, 0, stream>>>(
        H, W2, scale1, shift1, nullptr, dinv, (float*)Ut, nullptr, N);
    agg_kernel<128, true, true><<<(N + 15) / 16, 256, 0, stream>>>(
        Ut, csr, offs, deg, dinv, b2, H, stats2, N);
    finalize_kernel<128><<<1, 128, 0, stream>>>(stats2, g2, be2, scale2, shift2, N);

    // Layer 3: GEMM (BN2+GELU fused, fp16 out 64) -> Ut; agg(+b3,+stats3) -> H3
    gemm_kernel<128, 64, true, false, true, true, false><<<(N + 63) / 64, 256, 0, stream>>>(
        H, W3, scale2, shift2, nullptr, dinv, (float*)Ut, nullptr, N);
    agg_kernel<64, true, true><<<(N + 31) / 32, 256, 0, stream>>>(
        Ut, csr, offs, deg, dinv, b3, H, stats3, N);

    // Epilogue: BN3+GELU+residual+meanpool, then head MLP
    norm_pool_kernel<<<1024, 256, 0, stream>>>(H, x, stats3, g3, be3, pool, N);
    mlp_kernel<<<1, 128, 0, stream>>>(pool, fc1w, fc1b, fc2w, fc2b, fc3w, fc3b,
                                      fc4w, fc4b, (float*)d_out, N);
}

// Round 5
// 711.875 us; speedup vs baseline: 1.3876x; 1.0193x over previous
//
#include <hip/hip_runtime.h>
#include <hip/hip_bf16.h>
#include <hip/hip_fp16.h>
#include <math.h>

// GNN: 3-layer GCN + BN + GELU + residual + meanpool + MLP -> scalar.
// R5: fp16 gather table (R4, halves bytes) + RESTORED memory-level parallelism:
// gather loop unrolled x4 with raw uint4 staging -> 4 independent loads in
// flight before any cvt/add (R4's unroll-2 was the regression: 165us vs R2's
// 124us despite half the bytes). GEMM fusions/stats unchanged.

__device__ __forceinline__ float gelu_f(float x) {
    return 0.5f * x * (1.0f + erff(x * 0.7071067811865476f));
}

__device__ __forceinline__ int wave_incl_scan(int v, int lane) {
#pragma unroll
    for (int off = 1; off < 64; off <<= 1) {
        int t = __shfl_up(v, (unsigned)off, 64);
        if (lane >= off) v += t;
    }
    return v;
}

__device__ __forceinline__ void load8h(const __half* __restrict__ p, float* f) {
    uint4 u = *(const uint4*)p;
    const __half2* h2p = (const __half2*)&u;
#pragma unroll
    for (int i = 0; i < 4; i++) {
        float2 t = __half22float2(h2p[i]);
        f[2 * i] = t.x;
        f[2 * i + 1] = t.y;
    }
}

__device__ __forceinline__ void acc8h(const uint4& u, float* f) {
    const __half2* h2p = (const __half2*)&u;
#pragma unroll
    for (int i = 0; i < 4; i++) {
        float2 t = __half22float2(h2p[i]);
        f[2 * i] += t.x;
        f[2 * i + 1] += t.y;
    }
}

// ---- init: deg = 1.0 (self loop), zero double accumulators ----
__global__ void init_kernel(float* __restrict__ deg, double* __restrict__ dbls,
                            int n, int ndbl) {
    int i = blockIdx.x * 256 + threadIdx.x;
    if (i < n) deg[i] = 1.0f;
    if (i < ndbl) dbls[i] = 0.0;
}

__global__ void degree_kernel(const int* __restrict__ col, float* __restrict__ deg, int E) {
    int e = blockIdx.x * 256 + threadIdx.x;
    if (e < E) atomicAdd(&deg[col[e]], 1.0f);
}

__global__ __launch_bounds__(256) void scan1_kernel(const float* __restrict__ deg,
                                                    float* __restrict__ dinv,
                                                    int* __restrict__ offs,
                                                    int* __restrict__ bsums, int n) {
    int i = blockIdx.x * 256 + threadIdx.x;
    int lane = threadIdx.x & 63;
    int wid = threadIdx.x >> 6;
    int cnt = 0;
    if (i < n) {
        float d = deg[i];
        dinv[i] = 1.0f / sqrtf(d);
        cnt = (int)d - 1;
    }
    int incl = wave_incl_scan(cnt, lane);
    __shared__ int ws[4];
    if (lane == 63) ws[wid] = incl;
    __syncthreads();
    if (threadIdx.x == 0) {
        int a = 0;
#pragma unroll
        for (int j = 0; j < 4; j++) { int t = ws[j]; ws[j] = a; a += t; }
        bsums[blockIdx.x] = a;
    }
    __syncthreads();
    int excl = incl - cnt + ws[wid];
    if (i < n) offs[i] = excl;
}

__global__ __launch_bounds__(512) void scan2_kernel(int* __restrict__ bsums, int nblk) {
    int lane = threadIdx.x & 63;
    int wid = threadIdx.x >> 6;
    int v = (threadIdx.x < nblk) ? bsums[threadIdx.x] : 0;
    int incl = wave_incl_scan(v, lane);
    __shared__ int ws[8];
    if (lane == 63) ws[wid] = incl;
    __syncthreads();
    if (threadIdx.x == 0) {
        int a = 0;
#pragma unroll
        for (int j = 0; j < 8; j++) { int t = ws[j]; ws[j] = a; a += t; }
    }
    __syncthreads();
    int excl = incl - v + ws[wid];
    if (threadIdx.x < nblk) bsums[threadIdx.x] = excl;
}

__global__ void scan3_kernel(int* __restrict__ offs, const int* __restrict__ bsums,
                             int* __restrict__ cursor, int n) {
    int i = blockIdx.x * 256 + threadIdx.x;
    if (i < n) {
        int o = offs[i] + bsums[i >> 8];
        offs[i] = o;
        cursor[i] = o;
    }
}

__global__ void fill_kernel(const int* __restrict__ row, const int* __restrict__ col,
                            int* __restrict__ cursor, int* __restrict__ csr, int E) {
    int e = blockIdx.x * 256 + threadIdx.x;
    if (e < E) {
        int c = col[e];
        int pos = atomicAdd(&cursor[c], 1);
        csr[pos] = row[e];
    }
}

// ---- convert x[N][64] fp32 -> xh[N][64] fp16, scaled by dinv[node] ----
__global__ __launch_bounds__(256) void halfconv_kernel(const float* __restrict__ x,
                                                       const float* __restrict__ dinv,
                                                       __half* __restrict__ xh, int N) {
    int t = blockIdx.x * 256 + threadIdx.x;   // one 8-float chunk per thread
    if (t >= N * 8) return;
    int node = t >> 3;
    float dv = dinv[node];
    const float4* p = (const float4*)(x + (size_t)t * 8);
    float4 a = p[0], b = p[1];
    __half2 h[4];
    h[0] = __floats2half2_rn(a.x * dv, a.y * dv);
    h[1] = __floats2half2_rn(a.z * dv, a.w * dv);
    h[2] = __floats2half2_rn(b.x * dv, b.y * dv);
    h[3] = __floats2half2_rn(b.z * dv, b.w * dv);
    *(uint4*)(xh + (size_t)t * 8) = *(uint4*)h;
}

// ---- aggregation: H[i][D] = dinv_i*(Ut[i] + sum in-edge Ut[src]) (+bias) ----
// Ut fp16 row-major, pre-scaled by dinv[src]; fp32 accumulate.
// GPN = D/8 threads per node (16B gathers); x4 unrolled -> 4 loads in flight.
template <int D, bool STATS, bool BIAS>
__global__ __launch_bounds__(256) void agg_kernel(const __half* __restrict__ Ut,
                                                  const int* __restrict__ csr,
                                                  const int* __restrict__ offs,
                                                  const float* __restrict__ deg,
                                                  const float* __restrict__ dinv,
                                                  const float* __restrict__ bias,
                                                  float* __restrict__ H,
                                                  double* __restrict__ stats, int n) {
    constexpr int GPN = D / 8;
    constexpr int NPB = 256 / GPN;
    int g = threadIdx.x / GPN;
    int cl = threadIdx.x % GPN;
    int node = blockIdx.x * NPB + g;
    bool act = node < n;

    float a[8], b[8];
#pragma unroll
    for (int c = 0; c < 8; c++) { a[c] = 0.f; b[c] = 0.f; }

    int start = 0, cnt = 0;
    float dvi = 0.f;
    if (act) {
        start = offs[node];
        cnt = (int)deg[node] - 1;
        dvi = dinv[node];
        load8h(Ut + (size_t)node * D + cl * 8, a);   // self loop (pre-scaled)
    }
    const __half* __restrict__ base = Ut + cl * 8;
    int j = 0;
    for (; j + 4 <= cnt; j += 4) {
        int s0 = csr[start + j];
        int s1 = csr[start + j + 1];
        int s2 = csr[start + j + 2];
        int s3 = csr[start + j + 3];
        uint4 u0 = *(const uint4*)(base + (size_t)s0 * D);
        uint4 u1 = *(const uint4*)(base + (size_t)s1 * D);
        uint4 u2 = *(const uint4*)(base + (size_t)s2 * D);
        uint4 u3 = *(const uint4*)(base + (size_t)s3 * D);
        acc8h(u0, a);
        acc8h(u1, b);
        acc8h(u2, a);
        acc8h(u3, b);
    }
    if (j + 2 <= cnt) {
        int s0 = csr[start + j];
        int s1 = csr[start + j + 1];
        uint4 u0 = *(const uint4*)(base + (size_t)s0 * D);
        uint4 u1 = *(const uint4*)(base + (size_t)s1 * D);
        acc8h(u0, a);
        acc8h(u1, b);
        j += 2;
    }
    if (j < cnt) {
        int s0 = csr[start + j];
        uint4 u0 = *(const uint4*)(base + (size_t)s0 * D);
        acc8h(u0, a);
    }

    float h[8];
#pragma unroll
    for (int c = 0; c < 8; c++) h[c] = (a[c] + b[c]) * dvi;
    if (BIAS) {
#pragma unroll
        for (int c = 0; c < 8; c++) h[c] += bias[cl * 8 + c];
    }
    if (act) {
        float* dst = H + (size_t)node * D + cl * 8;
        *(float4*)dst = make_float4(h[0], h[1], h[2], h[3]);
        *(float4*)(dst + 4) = make_float4(h[4], h[5], h[6], h[7]);
    } else {
#pragma unroll
        for (int c = 0; c < 8; c++) h[c] = 0.f;   // no stats contribution
    }

    if (STATS) {
        float s[8], q[8];
#pragma unroll
        for (int c = 0; c < 8; c++) { s[c] = h[c]; q[c] = h[c] * h[c]; }
#pragma unroll
        for (int m = GPN; m < 64; m <<= 1) {
#pragma unroll
            for (int c = 0; c < 8; c++) {
                s[c] += __shfl_xor(s[c], m, 64);
                q[c] += __shfl_xor(q[c], m, 64);
            }
        }
        __shared__ float ps[4][GPN][8], pq[4][GPN][8];
        int wid = threadIdx.x >> 6;
        int lane = threadIdx.x & 63;
        if (lane < GPN) {
#pragma unroll
            for (int c = 0; c < 8; c++) { ps[wid][lane][c] = s[c]; pq[wid][lane][c] = q[c]; }
        }
        __syncthreads();
        if (threadIdx.x < D) {
            int cgi = threadIdx.x >> 3, ci = threadIdx.x & 7;
            float t1 = ps[0][cgi][ci] + ps[1][cgi][ci] + ps[2][cgi][ci] + ps[3][cgi][ci];
            float t2 = pq[0][cgi][ci] + pq[1][cgi][ci] + pq[2][cgi][ci] + pq[3][cgi][ci];
            atomicAdd(&stats[threadIdx.x], (double)t1);
            atomicAdd(&stats[D + threadIdx.x], (double)t2);
        }
    }
}

// ---- register-blocked GEMM ----
template <int DIN, int DOUT, bool BNIN, bool BIAS, bool DINVOUT, bool HALFOUT, bool STATS>
__global__ __launch_bounds__(256) void gemm_kernel(const float* __restrict__ Hin,
                                                   const float* __restrict__ W,
                                                   const float* __restrict__ scale,
                                                   const float* __restrict__ shift,
                                                   const float* __restrict__ bias,
                                                   const float* __restrict__ dinv,
                                                   float* __restrict__ Out,
                                                   double* __restrict__ stats, int n) {
    constexpr int BNODES = 64;
    constexpr int KT = 32;
    constexpr int HP = DIN + 4;
    constexpr int VC = DOUT / 16;      // 8 (DOUT=128) or 4 (DOUT=64)
    constexpr int C4 = VC / 4;
    __shared__ float Hs[BNODES * HP];
    __shared__ float Ws[KT * DOUT];
    __shared__ float ps[STATS ? 4 : 1][16][VC];
    __shared__ float pq[STATS ? 4 : 1][16][VC];

    int node0 = blockIdx.x * BNODES;
    int nv = n - node0;
    if (nv > BNODES) nv = BNODES;
    int cg = threadIdx.x & 15;
    int ng = threadIdx.x >> 4;

    constexpr int F4 = BNODES * (DIN / 4);
    for (int f = threadIdx.x; f < F4; f += 256) {
        int nn = f / (DIN / 4);
        int k4 = f - nn * (DIN / 4);
        float4 v = make_float4(0.f, 0.f, 0.f, 0.f);
        if (nn < nv)
            v = *(const float4*)(Hin + (size_t)(node0 + nn) * DIN + k4 * 4);
        if (BNIN) {
            float4 sc = *(const float4*)(scale + k4 * 4);
            float4 sh = *(const float4*)(shift + k4 * 4);
            v.x = gelu_f(fmaf(v.x, sc.x, sh.x));
            v.y = gelu_f(fmaf(v.y, sc.y, sh.y));
            v.z = gelu_f(fmaf(v.z, sc.z, sh.z));
            v.w = gelu_f(fmaf(v.w, sc.w, sh.w));
        }
        *(float4*)(Hs + nn * HP + k4 * 4) = v;
    }

    float acc[4][VC];
#pragma unroll
    for (int i = 0; i < 4; i++)
#pragma unroll
        for (int c = 0; c < VC; c++) acc[i][c] = 0.0f;

    for (int kb = 0; kb < DIN; kb += KT) {
        __syncthreads();
        for (int f = threadIdx.x; f < KT * DOUT / 4; f += 256)
            *(float4*)(Ws + f * 4) = *(const float4*)(W + (size_t)kb * DOUT + f * 4);
        __syncthreads();
#pragma unroll
        for (int kk = 0; kk < KT; kk++) {
            float h[4];
#pragma unroll
            for (int i = 0; i < 4; i++)
                h[i] = Hs[(ng * 4 + i) * HP + kb + kk];
            float w[VC];
#pragma unroll
            for (int c = 0; c < C4; c++) {
                float4 w4 = *(const float4*)(Ws + kk * DOUT + cg * VC + c * 4);
                w[c * 4 + 0] = w4.x; w[c * 4 + 1] = w4.y;
                w[c * 4 + 2] = w4.z; w[c * 4 + 3] = w4.w;
            }
#pragma unroll
            for (int i = 0; i < 4; i++)
#pragma unroll
                for (int c = 0; c < VC; c++)
                    acc[i][c] = fmaf(h[i], w[c], acc[i][c]);
        }
    }

    float fin[4][VC];
#pragma unroll
    for (int i = 0; i < 4; i++) {
        int nn = ng * 4 + i;
        bool valid = nn < nv;
        int node = node0 + nn;
        float dv = 1.0f;
        if (DINVOUT && valid) dv = dinv[node];
#pragma unroll
        for (int c = 0; c < VC; c++) {
            float f = acc[i][c] * dv;
            if (BIAS) f += bias[cg * VC + c];
            fin[i][c] = valid ? f : 0.f;
        }
        if (valid) {
            if (HALFOUT) {
                __half* hp = (__half*)Out + (size_t)node * DOUT + cg * VC;
                if (VC == 8) {
                    __half2 pk[4];
                    pk[0] = __floats2half2_rn(fin[i][0], fin[i][1]);
                    pk[1] = __floats2half2_rn(fin[i][2], fin[i][3]);
                    pk[2] = __floats2half2_rn(fin[i][4], fin[i][5]);
                    pk[3] = __floats2half2_rn(fin[i][6], fin[i][7]);
                    *(uint4*)hp = *(uint4*)pk;
                } else {
                    __half2 pk[2];
                    pk[0] = __floats2half2_rn(fin[i][0], fin[i][1]);
                    pk[1] = __floats2half2_rn(fin[i][2], fin[i][3]);
                    *(uint2*)hp = *(uint2*)pk;
                }
            } else {
#pragma unroll
                for (int c = 0; c < C4; c++)
                    *(float4*)(Out + (size_t)node * DOUT + cg * VC + c * 4) =
                        make_float4(fin[i][c * 4 + 0], fin[i][c * 4 + 1],
                                    fin[i][c * 4 + 2], fin[i][c * 4 + 3]);
            }
        }
    }

    if (STATS) {
        float s[VC], q[VC];
#pragma unroll
        for (int c = 0; c < VC; c++) {
            s[c] = fin[0][c] + fin[1][c] + fin[2][c] + fin[3][c];
            q[c] = fin[0][c] * fin[0][c] + fin[1][c] * fin[1][c] +
                   fin[2][c] * fin[2][c] + fin[3][c] * fin[3][c];
        }
#pragma unroll
        for (int st = 16; st < 64; st <<= 1) {
#pragma unroll
            for (int c = 0; c < VC; c++) {
                s[c] += __shfl_xor(s[c], st, 64);
                q[c] += __shfl_xor(q[c], st, 64);
            }
        }
        int wid = threadIdx.x >> 6;
        int lane = threadIdx.x & 63;
        if (lane < 16) {
#pragma unroll
            for (int c = 0; c < VC; c++) { ps[wid][lane][c] = s[c]; pq[wid][lane][c] = q[c]; }
        }
        __syncthreads();
        if (threadIdx.x < DOUT) {
            int col = threadIdx.x;
            int cgi = col / VC, ci = col % VC;
            float t = ps[0][cgi][ci] + ps[1][cgi][ci] + ps[2][cgi][ci] + ps[3][cgi][ci];
            float t2 = pq[0][cgi][ci] + pq[1][cgi][ci] + pq[2][cgi][ci] + pq[3][cgi][ci];
            atomicAdd(&stats[col], (double)t);
            atomicAdd(&stats[DOUT + col], (double)t2);
        }
    }
}

// ---- stats sums -> per-channel scale/shift floats ----
template <int D>
__global__ void finalize_kernel(const double* __restrict__ stats,
                                const float* __restrict__ g, const float* __restrict__ be,
                                float* __restrict__ scale, float* __restrict__ shift, int n) {
    int c = threadIdx.x;
    if (c < D) {
        double mu = stats[c] / n;
        double var = stats[c + D] / n - mu * mu;
        double inv = 1.0 / sqrt(var + 1e-5);
        double sc = (double)g[c] * inv;
        scale[c] = (float)sc;
        shift[c] = (float)((double)be[c] - mu * sc);
    }
}

// ---- layer-3: BN normalize + GELU + residual(x) + mean-pool accumulate ----
__global__ __launch_bounds__(256) void norm_pool_kernel(const float* __restrict__ X3,
                                                        const float* __restrict__ x0,
                                                        const double* __restrict__ stats,
                                                        const float* __restrict__ gw,
                                                        const float* __restrict__ be,
                                                        double* __restrict__ pool, int n) {
    constexpr int D = 64;
    constexpr int RPB = 4;
    int c = threadIdx.x % D;
    double mu = stats[c] / n;
    double var = stats[c + D] / n - mu * mu;
    double inv = 1.0 / sqrt(var + 1e-5);
    float scale = (float)((double)gw[c] * inv);
    float shift = (float)((double)be[c] - mu * (double)gw[c] * inv);
    int r0 = threadIdx.x / D;
    int rowsPerGrid = gridDim.x * RPB;
    double s = 0.0;
    for (int r = blockIdx.x * RPB + r0; r < n; r += rowsPerGrid) {
        size_t idx = (size_t)r * D + c;
        float t = fmaf(X3[idx], scale, shift);
        float res = x0[idx] + gelu_f(t);
        s += res;
    }
    __shared__ double sh[256];
    sh[threadIdx.x] = s;
    __syncthreads();
    if (threadIdx.x < D) {
#pragma unroll
        for (int j = 1; j < RPB; j++) s += sh[threadIdx.x + j * D];
        atomicAdd(&pool[c], s);
    }
}

// ---- head MLP: 64 ->128 ->64 ->32 ->1, single block ----
__global__ __launch_bounds__(128) void mlp_kernel(const double* __restrict__ pool,
                                                  const float* __restrict__ w1, const float* __restrict__ b1,
                                                  const float* __restrict__ w2, const float* __restrict__ b2,
                                                  const float* __restrict__ w3, const float* __restrict__ b3,
                                                  const float* __restrict__ w4, const float* __restrict__ b4,
                                                  float* __restrict__ out, int n) {
    __shared__ float v0[64], h1[128], h2[64], h3[32];
    int t = threadIdx.x;
    if (t < 64) v0[t] = (float)(pool[t] / (double)n);
    __syncthreads();
    if (t < 128) {
        float a = b1[t];
        for (int k = 0; k < 64; k++) a = fmaf(v0[k], w1[k * 128 + t], a);
        h1[t] = gelu_f(a);
    }
    __syncthreads();
    if (t < 64) {
        float a = b2[t];
        for (int k = 0; k < 128; k++) a = fmaf(h1[k], w2[k * 64 + t], a);
        h2[t] = gelu_f(a);
    }
    __syncthreads();
    if (t < 32) {
        float a = b3[t];
        for (int k = 0; k < 64; k++) a = fmaf(h2[k], w3[k * 32 + t], a);
        h3[t] = gelu_f(a);
    }
    __syncthreads();
    if (t == 0) {
        float a = b4[0];
        for (int k = 0; k < 32; k++) a = fmaf(h3[k], w4[k], a);
        out[0] = a;
    }
}

extern "C" void kernel_launch(void* const* d_in, const int* in_sizes, int n_in,
                              void* d_out, int out_size, void* d_ws, size_t ws_size,
                              hipStream_t stream) {
    const float* x    = (const float*)d_in[0];
    const int*   ei   = (const int*)d_in[1];
    const float* W1   = (const float*)d_in[2];
    const float* b1   = (const float*)d_in[3];
    const float* g1   = (const float*)d_in[4];
    const float* be1  = (const float*)d_in[5];
    const float* W2   = (const float*)d_in[6];
    const float* b2   = (const float*)d_in[7];
    const float* g2   = (const float*)d_in[8];
    const float* be2  = (const float*)d_in[9];
    const float* W3   = (const float*)d_in[10];
    const float* b3   = (const float*)d_in[11];
    const float* g3   = (const float*)d_in[12];
    const float* be3  = (const float*)d_in[13];
    const float* fc1w = (const float*)d_in[14];
    const float* fc1b = (const float*)d_in[15];
    const float* fc2w = (const float*)d_in[16];
    const float* fc2b = (const float*)d_in[17];
    const float* fc3w = (const float*)d_in[18];
    const float* fc3b = (const float*)d_in[19];
    const float* fc4w = (const float*)d_in[20];
    const float* fc4b = (const float*)d_in[21];

    const int N = in_sizes[0] / 64;
    const int E = in_sizes[1] / 2;
    const int* e_row = ei;       // source
    const int* e_col = ei + E;   // target (aggregation index)

    // ---- workspace layout (~110 MB) ----
    char* ws = (char*)d_ws;
    size_t off = 0;
    double* stats1 = (double*)(ws + off); off += 256 * sizeof(double);
    double* stats2 = (double*)(ws + off); off += 256 * sizeof(double);
    double* stats3 = (double*)(ws + off); off += 256 * sizeof(double);
    double* pool   = (double*)(ws + off); off += 64 * sizeof(double);
    float* scale1 = (float*)(ws + off); off += 128 * sizeof(float);
    float* shift1 = (float*)(ws + off); off += 128 * sizeof(float);
    float* scale2 = (float*)(ws + off); off += 128 * sizeof(float);
    float* shift2 = (float*)(ws + off); off += 128 * sizeof(float);
    float* deg   = (float*)(ws + off); off += (size_t)N * sizeof(float);
    float* dinv  = (float*)(ws + off); off += (size_t)N * sizeof(float);
    off = (off + 15) & ~(size_t)15;
    int* offs    = (int*)(ws + off); off += (size_t)N * sizeof(int);
    int* cursor  = (int*)(ws + off); off += (size_t)N * sizeof(int);
    int* bsums   = (int*)(ws + off); off += 512 * sizeof(int);
    int* csr     = (int*)(ws + off); off += (size_t)E * sizeof(int);
    off = (off + 255) & ~(size_t)255;
    __half* Ut   = (__half*)(ws + off); off += (size_t)N * 128 * sizeof(__half);  // fp16 gather table
    float* A1    = (float*)(ws + off);  off += (size_t)N * 64 * sizeof(float);    // agg1 out (fp32)
    float* H     = (float*)(ws + off);  off += (size_t)N * 128 * sizeof(float);   // fp32 row-major
    __half* xh   = Ut;  // alias: xh dead after agg1, before gemm2 writes Ut

    const int nb256 = (N + 255) / 256;
    const int ebl = (E + 255) / 256;

    init_kernel<<<nb256, 256, 0, stream>>>(deg, stats1, N, 832);
    degree_kernel<<<ebl, 256, 0, stream>>>(e_col, deg, E);
    scan1_kernel<<<nb256, 256, 0, stream>>>(deg, dinv, offs, bsums, N);
    scan2_kernel<<<1, 512, 0, stream>>>(bsums, nb256);
    scan3_kernel<<<nb256, 256, 0, stream>>>(offs, bsums, cursor, N);
    fill_kernel<<<ebl, 256, 0, stream>>>(e_row, e_col, cursor, csr, E);

    // Layer 1: x -> fp16 (dinv-scaled); agg 64-dim -> A1; GEMM(+b1,+stats1) -> H1
    halfconv_kernel<<<(N * 8 + 255) / 256, 256, 0, stream>>>(x, dinv, xh, N);
    agg_kernel<64, false, false><<<(N + 31) / 32, 256, 0, stream>>>(
        xh, csr, offs, deg, dinv, nullptr, A1, nullptr, N);
    gemm_kernel<64, 128, false, true, false, false, true><<<(N + 63) / 64, 256, 0, stream>>>(
        A1, W1, nullptr, nullptr, b1, dinv, H, stats1, N);
    finalize_kernel<128><<<1, 128, 0, stream>>>(stats1, g1, be1, scale1, shift1, N);

    // Layer 2: GEMM (BN1+GELU fused, dinv-scaled, fp16 out) -> Ut; agg(+b2,+stats2) -> H2
    gemm_kernel<128, 128, true, false, true, true, false><<<(N + 63) / 64, 256, 0, stream>>>(
        H, W2, scale1, shift1, nullptr, dinv, (float*)Ut, nullptr, N);
    agg_kernel<128, true, true><<<(N + 15) / 16, 256, 0, stream>>>(
        Ut, csr, offs, deg, dinv, b2, H, stats2, N);
    finalize_kernel<128><<<1, 128, 0, stream>>>(stats2, g2, be2, scale2, shift2, N);

    // Layer 3: GEMM (BN2+GELU fused, fp16 out 64) -> Ut; agg(+b3,+stats3) -> H3
    gemm_kernel<128, 64, true, false, true, true, false><<<(N + 63) / 64, 256, 0, stream>>>(
        H, W3, scale2, shift2, nullptr, dinv, (float*)Ut, nullptr, N);
    agg_kernel<64, true, true><<<(N + 31) / 32, 256, 0, stream>>>(
        Ut, csr, offs, deg, dinv, b3, H, stats3, N);

    // Epilogue: BN3+GELU+residual+meanpool, then head MLP
    norm_pool_kernel<<<1024, 256, 0, stream>>>(H, x, stats3, g3, be3, pool, N);
    mlp_kernel<<<1, 128, 0, stream>>>(pool, fc1w, fc1b, fc2w, fc2b, fc3w, fc3b,
                                      fc4w, fc4b, (float*)d_out, N);
}